// Round 19
// baseline (880.831 us; speedup 1.0000x reference)
//
#include <hip/hip_runtime.h>
#include <cstdint>

typedef _Float16 f16x8 __attribute__((ext_vector_type(8)));
typedef float f32x4 __attribute__((ext_vector_type(4)));

#define MDIM 24000   // N*T rows
#define DDIM 1024
#define CDIM 20
#define TDIM 750
#define NBATCH 32
#define KSEL 657
#define MASKV -100.0f
#define OMEGAF 0.6f
#define SPLIT_SCALE 2048.0f
#define SPLIT_INV   4.8828125e-4f   // 2^-11 exact

// d_out element offsets (x_r, cls_x_r, cls_x_ra, x_f, cls_x_f, cls_x_fa, tcam)
#define OFF_XR     0L
#define OFF_CLSX_R 24576000L
#define OFF_CLSRA  25056000L
#define OFF_XF     25536000L
#define OFF_CLSX_F 50112000L
#define OFF_CLSFA  50592000L
#define OFF_TCAM   51072000L

#define GLOAD16(g, l) __builtin_amdgcn_global_load_lds( \
    (const __attribute__((address_space(1))) void*)(g), \
    (__attribute__((address_space(3))) void*)(l), 16, 0, 0)

#define SBAR0() __builtin_amdgcn_sched_barrier(0)

// ---------------------------------------------------------------------------
// weight-split helpers (input splits fused into layer-1)
// ---------------------------------------------------------------------------
__global__ __launch_bounds__(256)
void split_w4(const float* __restrict__ W0, const float* __restrict__ W1,
              const float* __restrict__ W2, const float* __restrict__ W3,
              _Float16* __restrict__ Dbase) {
    const int wi = blockIdx.x >> 9;                 // 0..3
    const int bid = blockIdx.x & 511;
    const float* __restrict__ src = (wi == 0) ? W0 : (wi == 1) ? W1 : (wi == 2) ? W2 : W3;
    _Float16* __restrict__ D0 = Dbase + (long)(2 * wi) * 1048576L;
    _Float16* __restrict__ D1 = D0 + 1048576L;
    for (long v = (long)bid * 256 + threadIdx.x; v < 131072L; v += 512L * 256) {
        const long row = v >> 7;
        const int c8 = (int)(v & 127) << 3;
        const float4 x0 = *reinterpret_cast<const float4*>(&src[row * 1024 + c8]);
        const float4 x1 = *reinterpret_cast<const float4*>(&src[row * 1024 + c8 + 4]);
        float xs[8] = {x0.x, x0.y, x0.z, x0.w, x1.x, x1.y, x1.z, x1.w};
        f16x8 h0, h1;
#pragma unroll
        for (int j = 0; j < 8; ++j) {
            const _Float16 a = (_Float16)xs[j];
            h0[j] = a;
            h1[j] = (_Float16)((xs[j] - (float)a) * SPLIT_SCALE);
        }
        *reinterpret_cast<f16x8*>(&D0[v << 3]) = h0;
        *reinterpret_cast<f16x8*>(&D1[v << 3]) = h1;
    }
}

__global__ __launch_bounds__(256)
void split_clsW2(const float* __restrict__ Wc_r, const float* __restrict__ Wa_r,
                 const float* __restrict__ Wc_f, const float* __restrict__ Wa_f,
                 _Float16* __restrict__ Dbase) {
    const int z = blockIdx.x >> 8;                  // 0..1
    const int idx = (blockIdx.x & 255) * 256 + threadIdx.x;   // 0..65535
    const float* __restrict__ Wc = z ? Wc_f : Wc_r;
    const float* __restrict__ Wa = z ? Wa_f : Wa_r;
    _Float16* __restrict__ D0 = Dbase + (long)z * 131072L;
    _Float16* __restrict__ D1 = D0 + 65536L;
    const int r = idx >> 10;
    const int c = idx & 1023;
    float v = 0.f;
    if (r < 20)      v = Wc[r * 1024 + c];
    else if (r < 40) v = Wa[(r - 20) * 1024 + c];
    const _Float16 h0 = (_Float16)v;
    D0[idx] = h0;
    D1[idx] = (_Float16)((v - (float)h0) * SPLIT_SCALE);
}

// ---------------------------------------------------------------------------
// Layer-1 GEMM: A staged RAW FP32 (stride 2048), split in-register.
// r19: the f32->f16 split conversion moved BEFORE barrier B (it depends only
// on xlo/xhi certified by the lgkmcnt(0), is register-only, touches no LDS)
// -- each wave converts inside the barrier-wait slack while slower waves
// drain reads; the post-barrier path is pure MFMA.
// FP32 rows swizzled 16B-chunk XOR (chunk^=row&7) on BOTH sides (rule 21).
// ---------------------------------------------------------------------------
__global__ __launch_bounds__(256, 2)
void gemm_l1_f32a(const float* __restrict__ Ax,          // + stream offset
                  const _Float16* __restrict__ B0, const _Float16* __restrict__ B1,
                  const float* __restrict__ bias,
                  _Float16* __restrict__ H0, _Float16* __restrict__ H1) {
    __shared__ _Float16 sm[32768];   // 64 KiB
    uint8_t* const smb = (uint8_t*)sm;
    const int t = threadIdx.x;
    const int lane = t & 63;
    const int wave = t >> 6;
    const int wr = wave >> 1, wc = wave & 1;
    const int lr = lane & 15, lk = lane >> 4;
    const int wr4 = wr * 4, wc4 = wc * 4;

    const int bid = blockIdx.x;
    const int wg = (bid & 7) * 188 + (bid >> 3);
    const long bm = (long)(wg >> 3) * 128;
    const int bn = (wg & 7) * 128;

    const int irow = lane >> 3;                  // 0..7
    const int schunk = (lane & 7) ^ irow;        // swizzled source chunk
    const float* pA[4];
#pragma unroll
    for (int q = 0; q < 4; ++q) {
        long ra = bm + (wave * 4 + q) * 8 + irow;
        if (ra > MDIM - 1) ra = MDIM - 1;
        pA[q] = Ax + ra * 2048L + schunk * 4;
    }
    const int r_in = lane >> 2;
    const int c8 = (lane & 3) << 3;
    const long rb0 = (long)(bn + (wave * 2 + 0) * 16 + r_in);
    const long rb1 = (long)(bn + (wave * 2 + 1) * 16 + r_in);
    const _Float16* pB0a = B0 + (rb0 << 10) + c8;
    const _Float16* pB0b = B0 + (rb1 << 10) + c8;
    const _Float16* pB1a = B1 + (rb0 << 10) + c8;
    const _Float16* pB1b = B1 + (rb1 << 10) + c8;
    const int sb0 = (wave * 2 + 0) * 512 + lane * 8;
    const int sb1 = (wave * 2 + 1) * 512 + lane * 8;

#define STAGE8(par) do { \
    _Pragma("unroll") for (int q = 0; q < 4; ++q) { \
        GLOAD16(pA[q], smb + (par) * 32768 + (wave * 4 + q) * 1024 + lane * 16); \
        pA[q] += 32; } \
    _Float16* _d = sm + (par) * 16384; \
    GLOAD16(pB0a, _d + 8192 + sb0);  GLOAD16(pB0b, _d + 8192 + sb1); \
    GLOAD16(pB1a, _d + 12288 + sb0); GLOAD16(pB1b, _d + 12288 + sb1); \
    pB0a += 32; pB0b += 32; pB1a += 32; pB1b += 32; \
} while (0)

#define LDSB(tileoff, rb) (*(const f16x8*)&sm[cur * 16384 + (tileoff) + (rb) * 512 + lr * 32 + lk * 8])

    f32x4 accH[4][4], accL[4][4];
#pragma unroll
    for (int mi = 0; mi < 4; ++mi)
#pragma unroll
        for (int ni = 0; ni < 4; ++ni) {
            accH[mi][ni] = (f32x4){0.f, 0.f, 0.f, 0.f};
            accL[mi][ni] = (f32x4){0.f, 0.f, 0.f, 0.f};
        }

    f16x8 av0[4], av1[4], bv0[4], bv1[4];

#define COMPUTE() do { \
    SBAR0(); /* pin: reads stay AFTER barrier A */ \
    f32x4 xlo[4], xhi[4]; \
    _Pragma("unroll") for (int mi = 0; mi < 4; ++mi) { \
        const int r = wr4 * 16 + mi * 16 + lr; \
        const int ab = cur * 32768 + (r >> 3) * 1024 + (r & 7) * 128; \
        xlo[mi] = *(const f32x4*)(smb + ab + ((((lk * 2 + 0) ^ (r & 7))) << 4)); \
        xhi[mi] = *(const f32x4*)(smb + ab + ((((lk * 2 + 1) ^ (r & 7))) << 4)); \
    } \
    _Pragma("unroll") for (int ni = 0; ni < 4; ++ni) bv0[ni] = LDSB(8192,  wc4 + ni); \
    _Pragma("unroll") for (int ni = 0; ni < 4; ++ni) bv1[ni] = LDSB(12288, wc4 + ni); \
    asm volatile("s_waitcnt lgkmcnt(0)" ::: "memory"); \
    SBAR0(); \
    /* r19: conversion BEFORE barrier B -- register-only, hidden in the */ \
    /* barrier-wait slack; post-barrier path becomes pure MFMA. */ \
    _Pragma("unroll") for (int mi = 0; mi < 4; ++mi) { \
        f16x8 h0v, h1v; \
        _Pragma("unroll") for (int j = 0; j < 4; ++j) { \
            const _Float16 a = (_Float16)xlo[mi][j]; \
            h0v[j] = a; h1v[j] = (_Float16)((xlo[mi][j] - (float)a) * SPLIT_SCALE); \
        } \
        _Pragma("unroll") for (int j = 0; j < 4; ++j) { \
            const _Float16 a = (_Float16)xhi[mi][j]; \
            h0v[4 + j] = a; h1v[4 + j] = (_Float16)((xhi[mi][j] - (float)a) * SPLIT_SCALE); \
        } \
        av0[mi] = h0v; av1[mi] = h1v; \
    } \
    SBAR0(); \
    __builtin_amdgcn_s_barrier();  /* B: all waves consumed cur buf */ \
    SBAR0(); /* pin: MFMAs + next stage stay AFTER barrier B */ \
    __builtin_amdgcn_s_setprio(1); \
    _Pragma("unroll") for (int mi = 0; mi < 4; ++mi) \
    _Pragma("unroll") for (int ni = 0; ni < 4; ++ni) \
        accH[mi][ni] = __builtin_amdgcn_mfma_f32_16x16x32_f16(av0[mi], bv0[ni], accH[mi][ni], 0, 0, 0); \
    _Pragma("unroll") for (int mi = 0; mi < 4; ++mi) \
    _Pragma("unroll") for (int ni = 0; ni < 4; ++ni) \
        accL[mi][ni] = __builtin_amdgcn_mfma_f32_16x16x32_f16(av0[mi], bv1[ni], accL[mi][ni], 0, 0, 0); \
    _Pragma("unroll") for (int mi = 0; mi < 4; ++mi) \
    _Pragma("unroll") for (int ni = 0; ni < 4; ++ni) \
        accL[mi][ni] = __builtin_amdgcn_mfma_f32_16x16x32_f16(av1[mi], bv0[ni], accL[mi][ni], 0, 0, 0); \
    __builtin_amdgcn_s_setprio(0); \
} while (0)

    STAGE8(0);                       // tile 0 -> buf0 (8 loads in flight)
    for (int step = 0; step < 31; ++step) {
        const int cur = step & 1;
        STAGE8((step + 1) & 1);      // tile t+1 (8 newest loads)
        SBAR0();                     // pin: stage issued before the wait
        asm volatile("s_waitcnt vmcnt(8)" ::: "memory");  // tile t landed
        SBAR0();
        __builtin_amdgcn_s_barrier();                     // A: cur buf ready
        COMPUTE();
    }
    {   // peeled step 31
        const int cur = 1;
        SBAR0();
        asm volatile("s_waitcnt vmcnt(0)" ::: "memory");
        SBAR0();
        __builtin_amdgcn_s_barrier();
        COMPUTE();
    }

#pragma unroll
    for (int ni = 0; ni < 4; ++ni) {
        const int col = bn + wc * 64 + ni * 16 + lr;
        const float bb = bias[col];
#pragma unroll
        for (int mi = 0; mi < 4; ++mi) {
            const long rbase = bm + wr * 64 + mi * 16 + lk * 4;
#pragma unroll
            for (int r = 0; r < 4; ++r) {
                const long row = rbase + r;
                if (row < MDIM) {
                    const float v = accH[mi][ni][r] + SPLIT_INV * accL[mi][ni][r];
                    const float hv = fmaxf(v + bb, 0.f);
                    const _Float16 h0 = (_Float16)hv;
                    H0[row * DDIM + col] = h0;
                    H1[row * DDIM + col] = (_Float16)((hv - (float)h0) * SPLIT_SCALE);
                }
            }
        }
    }
#undef COMPUTE
#undef LDSB
#undef STAGE8
}

// ---------------------------------------------------------------------------
// Layer-2 GEMM (r8 validated skeleton, f16-split A via MODE2 outputs).
// ---------------------------------------------------------------------------
template<int MODE>
__global__ __launch_bounds__(256, 2)
void gemm_fused_f16(const _Float16* __restrict__ A0, const _Float16* __restrict__ A1,
                    const _Float16* __restrict__ B0, const _Float16* __restrict__ B1,
                    const float* __restrict__ bias,
                    float* __restrict__ outF,
                    _Float16* __restrict__ H0, _Float16* __restrict__ H1) {
    __shared__ _Float16 sm[32768];   // 2 x 16384 f16 (A0|A1|B0|B1 tiles)
    const int t = threadIdx.x;
    const int lane = t & 63;
    const int wave = t >> 6;
    const int wr = wave >> 1, wc = wave & 1;
    const int lr = lane & 15, lk = lane >> 4;
    const int wr4 = wr * 4, wc4 = wc * 4;

    const int bid = blockIdx.x;
    const int wg = (bid & 7) * 188 + (bid >> 3);
    const long bm = (long)(wg >> 3) * 128;
    const int bn = (wg & 7) * 128;

    const int r_in = lane >> 2;
    const int c8 = (lane & 3) << 3;
    long ra0 = bm + (wave * 2 + 0) * 16 + r_in; if (ra0 > MDIM - 1) ra0 = MDIM - 1;
    long ra1 = bm + (wave * 2 + 1) * 16 + r_in; if (ra1 > MDIM - 1) ra1 = MDIM - 1;
    const long rb0 = (long)(bn + (wave * 2 + 0) * 16 + r_in);
    const long rb1 = (long)(bn + (wave * 2 + 1) * 16 + r_in);
    const _Float16* pA0a = A0 + (ra0 << 10) + c8;
    const _Float16* pA0b = A0 + (ra1 << 10) + c8;
    const _Float16* pA1a = A1 + (ra0 << 10) + c8;
    const _Float16* pA1b = A1 + (ra1 << 10) + c8;
    const _Float16* pB0a = B0 + (rb0 << 10) + c8;
    const _Float16* pB0b = B0 + (rb1 << 10) + c8;
    const _Float16* pB1a = B1 + (rb0 << 10) + c8;
    const _Float16* pB1b = B1 + (rb1 << 10) + c8;
    const int sb0 = (wave * 2 + 0) * 512 + lane * 8;
    const int sb1 = (wave * 2 + 1) * 512 + lane * 8;

#define STAGE8(par) do { \
    _Float16* _d = sm + (par) * 16384; \
    GLOAD16(pA0a, _d + sb0);         GLOAD16(pA0b, _d + sb1); \
    GLOAD16(pA1a, _d + 4096 + sb0);  GLOAD16(pA1b, _d + 4096 + sb1); \
    GLOAD16(pB0a, _d + 8192 + sb0);  GLOAD16(pB0b, _d + 8192 + sb1); \
    GLOAD16(pB1a, _d + 12288 + sb0); GLOAD16(pB1b, _d + 12288 + sb1); \
    pA0a += 32; pA0b += 32; pA1a += 32; pA1b += 32; \
    pB0a += 32; pB0b += 32; pB1a += 32; pB1b += 32; \
} while (0)

#define LDSF(tileoff, rb) (*(const f16x8*)&sm[cur + (tileoff) + (rb) * 512 + lr * 32 + lk * 8])

    f32x4 accH[4][4], accL[4][4];
#pragma unroll
    for (int mi = 0; mi < 4; ++mi)
#pragma unroll
        for (int ni = 0; ni < 4; ++ni) {
            accH[mi][ni] = (f32x4){0.f, 0.f, 0.f, 0.f};
            accL[mi][ni] = (f32x4){0.f, 0.f, 0.f, 0.f};
        }

    f16x8 av0[4], av1[4], bv0[4], bv1[4];

#define COMPUTE() do { \
    SBAR0(); /* pin: reads stay AFTER barrier A */ \
    _Pragma("unroll") for (int mi = 0; mi < 4; ++mi) av0[mi] = LDSF(0,     wr4 + mi); \
    _Pragma("unroll") for (int mi = 0; mi < 4; ++mi) av1[mi] = LDSF(4096,  wr4 + mi); \
    _Pragma("unroll") for (int ni = 0; ni < 4; ++ni) bv0[ni] = LDSF(8192,  wc4 + ni); \
    _Pragma("unroll") for (int ni = 0; ni < 4; ++ni) bv1[ni] = LDSF(12288, wc4 + ni); \
    asm volatile("s_waitcnt lgkmcnt(0)" ::: "memory"); \
    SBAR0(); \
    __builtin_amdgcn_s_barrier();  /* B: all waves consumed cur buf */ \
    SBAR0(); /* pin: MFMAs + next stage stay AFTER barrier B */ \
    __builtin_amdgcn_s_setprio(1); \
    _Pragma("unroll") for (int mi = 0; mi < 4; ++mi) \
    _Pragma("unroll") for (int ni = 0; ni < 4; ++ni) \
        accH[mi][ni] = __builtin_amdgcn_mfma_f32_16x16x32_f16(av0[mi], bv0[ni], accH[mi][ni], 0, 0, 0); \
    _Pragma("unroll") for (int mi = 0; mi < 4; ++mi) \
    _Pragma("unroll") for (int ni = 0; ni < 4; ++ni) \
        accL[mi][ni] = __builtin_amdgcn_mfma_f32_16x16x32_f16(av0[mi], bv1[ni], accL[mi][ni], 0, 0, 0); \
    _Pragma("unroll") for (int mi = 0; mi < 4; ++mi) \
    _Pragma("unroll") for (int ni = 0; ni < 4; ++ni) \
        accL[mi][ni] = __builtin_amdgcn_mfma_f32_16x16x32_f16(av1[mi], bv0[ni], accL[mi][ni], 0, 0, 0); \
    __builtin_amdgcn_s_setprio(0); \
} while (0)

    STAGE8(0);
    for (int step = 0; step < 31; ++step) {
        const int cur = (step & 1) * 16384;
        STAGE8((step + 1) & 1);
        SBAR0();
        asm volatile("s_waitcnt vmcnt(8)" ::: "memory");
        SBAR0();
        __builtin_amdgcn_s_barrier();
        COMPUTE();
    }
    {
        const int cur = 16384;
        SBAR0();
        asm volatile("s_waitcnt vmcnt(0)" ::: "memory");
        SBAR0();
        __builtin_amdgcn_s_barrier();
        COMPUTE();
    }

#pragma unroll
    for (int ni = 0; ni < 4; ++ni) {
        const int col = bn + wc * 64 + ni * 16 + lr;
        const float bb = bias[col];
#pragma unroll
        for (int mi = 0; mi < 4; ++mi) {
            const long rbase = bm + wr * 64 + mi * 16 + lk * 4;
#pragma unroll
            for (int r = 0; r < 4; ++r) {
                const long row = rbase + r;
                if (row < MDIM) {
                    const float v = accH[mi][ni][r] + SPLIT_INV * accL[mi][ni][r];
                    const float hv = fmaxf(v + bb, 0.f);
                    if (MODE == 1 || MODE == 2) outF[row * DDIM + col] = hv;
                    if (MODE == 0 || MODE == 2) {
                        const _Float16 h0 = (_Float16)hv;
                        H0[row * DDIM + col] = h0;
                        H1[row * DDIM + col] = (_Float16)((hv - (float)h0) * SPLIT_SCALE);
                    }
                }
            }
        }
    }
#undef COMPUTE
#undef LDSF
#undef STAGE8
}

// ---------------------------------------------------------------------------
// cls/at heads via split-f16 MFMA (3-panel rel err ~2^-20 << mask budget).
// ---------------------------------------------------------------------------
__global__ __launch_bounds__(256, 2)
void cls_mfma_f16(const _Float16* __restrict__ A0, const _Float16* __restrict__ A1,
                  const _Float16* __restrict__ B0, const _Float16* __restrict__ B1,
                  const float* __restrict__ bc, const float* __restrict__ ba,
                  float* __restrict__ clsx, float* __restrict__ atout) {
    __shared__ _Float16 sm[16384];
    const int t = threadIdx.x;
    const int lane = t & 63;
    const int wave = t >> 6;
    const int lr = lane & 15, lk = lane >> 4;
    const long bm = (long)blockIdx.x * 64;

    const int r_in = lane >> 2;
    const int c8 = (lane & 3) << 3;
    const long raA = bm + wave * 16 + r_in;
    const long raB = (long)(wave * 16 + r_in);
    const _Float16* pA0 = A0 + (raA << 10) + c8;
    const _Float16* pA1 = A1 + (raA << 10) + c8;
    const _Float16* pB0 = B0 + (raB << 10) + c8;
    const _Float16* pB1 = B1 + (raB << 10) + c8;
    const int sb = wave * 512 + lane * 8;

#define CSTAGE(par) do { \
    _Float16* _d = sm + (par) * 8192; \
    GLOAD16(pA0, _d + sb); \
    GLOAD16(pA1, _d + 2048 + sb); \
    GLOAD16(pB0, _d + 4096 + sb); \
    GLOAD16(pB1, _d + 6144 + sb); \
    pA0 += 32; pA1 += 32; pB0 += 32; pB1 += 32; \
} while (0)

#define CLDS(tileoff, rb) (*(const f16x8*)&sm[cur + (tileoff) + (rb) * 512 + lr * 32 + lk * 8])

    f32x4 accH[3], accL[3];
#pragma unroll
    for (int ni = 0; ni < 3; ++ni) {
        accH[ni] = (f32x4){0.f, 0.f, 0.f, 0.f};
        accL[ni] = (f32x4){0.f, 0.f, 0.f, 0.f};
    }
    f16x8 av0, av1, bv0[3], bv1[3];

#define CCOMPUTE() do { \
    SBAR0(); \
    av0 = CLDS(0, wave); \
    av1 = CLDS(2048, wave); \
    _Pragma("unroll") for (int ni = 0; ni < 3; ++ni) bv0[ni] = CLDS(4096, ni); \
    _Pragma("unroll") for (int ni = 0; ni < 3; ++ni) bv1[ni] = CLDS(6144, ni); \
    asm volatile("s_waitcnt lgkmcnt(0)" ::: "memory"); \
    SBAR0(); \
    __builtin_amdgcn_s_barrier(); \
    SBAR0(); \
    _Pragma("unroll") for (int ni = 0; ni < 3; ++ni) \
        accH[ni] = __builtin_amdgcn_mfma_f32_16x16x32_f16(av0, bv0[ni], accH[ni], 0, 0, 0); \
    _Pragma("unroll") for (int ni = 0; ni < 3; ++ni) \
        accL[ni] = __builtin_amdgcn_mfma_f32_16x16x32_f16(av0, bv1[ni], accL[ni], 0, 0, 0); \
    _Pragma("unroll") for (int ni = 0; ni < 3; ++ni) \
        accL[ni] = __builtin_amdgcn_mfma_f32_16x16x32_f16(av1, bv0[ni], accL[ni], 0, 0, 0); \
} while (0)

    CSTAGE(0);
    for (int step = 0; step < 31; ++step) {
        const int cur = (step & 1) * 8192;
        CSTAGE((step + 1) & 1);
        SBAR0();
        asm volatile("s_waitcnt vmcnt(4)" ::: "memory");
        SBAR0();
        __builtin_amdgcn_s_barrier();
        CCOMPUTE();
    }
    {
        const int cur = 8192;
        SBAR0();
        asm volatile("s_waitcnt vmcnt(0)" ::: "memory");
        SBAR0();
        __builtin_amdgcn_s_barrier();
        CCOMPUTE();
    }

#pragma unroll
    for (int ni = 0; ni < 3; ++ni) {
        const int col = ni * 16 + lr;
        const float bvv = (col < 20) ? bc[col] : ((col < 40) ? ba[col - 20] : 0.f);
#pragma unroll
        for (int r = 0; r < 4; ++r) {
            const long row = bm + wave * 16 + lk * 4 + r;
            const float v = accH[ni][r] + SPLIT_INV * accL[ni][r] + bvv;
            if (col < 20)      clsx[row * CDIM + col] = v;
            else if (col < 40) atout[row * CDIM + col - 20] = v;
        }
    }
#undef CCOMPUTE
#undef CLDS
#undef CSTAGE
}

// ---------------------------------------------------------------------------
// Exact rank-KSEL: 4-pass radix-select, parallel digit scan.
// ---------------------------------------------------------------------------
__global__ __launch_bounds__(256)
void select_kth(const float* __restrict__ clsx_r, const float* __restrict__ clsx_f,
                float* __restrict__ kth) {
    __shared__ uint32_t su[TDIM];
    __shared__ uint32_t hist[256];
    __shared__ uint32_t sc[256];
    __shared__ uint32_t s_prefix, s_rank, s_mask;
    const int b = blockIdx.x;
    const int z = b / 640;
    const int rem = b - z * 640;
    const int n = rem / CDIM;
    const int c = rem - n * CDIM;
    const float* src = (z == 0) ? clsx_r : clsx_f;
    const int tid = threadIdx.x;

    for (int i = tid; i < TDIM; i += 256) {
        const uint32_t bits = __float_as_uint(src[((long)n * TDIM + i) * CDIM + c]);
        su[i] = (bits & 0x80000000u) ? ~bits : (bits | 0x80000000u);
    }
    if (tid == 0) { s_prefix = 0; s_rank = KSEL; s_mask = 0; }
    __syncthreads();

#pragma unroll
    for (int pass = 0; pass < 4; ++pass) {
        const int shift = 24 - pass * 8;
        hist[tid] = 0;
        __syncthreads();
        const uint32_t pfx = s_prefix, msk = s_mask, rk = s_rank;
        for (int i = tid; i < TDIM; i += 256) {
            const uint32_t u = su[i];
            if ((u & msk) == pfx) atomicAdd(&hist[(u >> shift) & 255u], 1u);
        }
        __syncthreads();
        sc[tid] = hist[tid];
        __syncthreads();
#pragma unroll
        for (int off = 1; off < 256; off <<= 1) {
            const uint32_t add = (tid >= off) ? sc[tid - off] : 0u;
            __syncthreads();
            sc[tid] += add;
            __syncthreads();
        }
        const uint32_t incl = sc[tid];
        const uint32_t excl = incl - hist[tid];
        if (excl < rk && incl >= rk) {
            s_prefix = pfx | ((uint32_t)tid << shift);
            s_rank   = rk - excl;
            s_mask   = msk | (0xffu << shift);
        }
        __syncthreads();
    }
    if (tid == 0) {
        const uint32_t u = s_prefix;
        kth[b] = (u & 0x80000000u) ? __uint_as_float(u ^ 0x80000000u)
                                   : __uint_as_float(~u);
    }
}

__global__ __launch_bounds__(256)
void final_mask(float* __restrict__ out, const float* __restrict__ kth,
                const float* __restrict__ mul_r, const float* __restrict__ mul_f) {
    const int idx = blockIdx.x * 256 + threadIdx.x;
    if (idx >= NBATCH * TDIM * CDIM) return;
    const int m = idx / CDIM;
    const int c = idx - m * CDIM;
    const int n = m / TDIM;
    const float xr  = out[OFF_CLSX_R + idx];
    const float xf  = out[OFF_CLSX_F + idx];
    const float atr = out[OFF_CLSRA + idx];
    const float atf = out[OFF_CLSFA + idx];
    const float kr = kth[n * CDIM + c];
    const float kf = kth[640 + n * CDIM + c];
    out[OFF_CLSRA + idx] = (xr > kr) ? MASKV : atr;
    out[OFF_CLSFA + idx] = (xf > kf) ? MASKV : atf;
    out[OFF_TCAM + idx]  = (xr + OMEGAF * atr) * mul_r[c] + (xf + OMEGAF * atf) * mul_f[c];
}

extern "C" void kernel_launch(void* const* d_in, const int* in_sizes, int n_in,
                              void* d_out, int out_size, void* d_ws, size_t ws_size,
                              hipStream_t stream) {
    const float* inp    = (const float*)d_in[0];
    const float* Wfc_r  = (const float*)d_in[1];
    const float* bfc_r  = (const float*)d_in[2];
    const float* Wfc1_r = (const float*)d_in[3];
    const float* bfc1_r = (const float*)d_in[4];
    const float* Wfc_f  = (const float*)d_in[5];
    const float* bfc_f  = (const float*)d_in[6];
    const float* Wfc1_f = (const float*)d_in[7];
    const float* bfc1_f = (const float*)d_in[8];
    const float* Wcls_r = (const float*)d_in[9];
    const float* bcls_r = (const float*)d_in[10];
    const float* Wcls_f = (const float*)d_in[11];
    const float* bcls_f = (const float*)d_in[12];
    const float* Wra    = (const float*)d_in[13];
    const float* bra    = (const float*)d_in[14];
    const float* Wfa    = (const float*)d_in[15];
    const float* bfa    = (const float*)d_in[16];
    const float* mul_r  = (const float*)d_in[17];
    const float* mul_f  = (const float*)d_in[18];

    float* out = (float*)d_out;
    _Float16* wsA0 = (_Float16*)d_ws;            // x splits (from layer-2 MODE2)
    _Float16* wsA1 = wsA0 + 24576000L;
    _Float16* wsH0 = wsA1 + 24576000L;
    _Float16* wsH1 = wsH0 + 24576000L;
    _Float16* wsW  = wsH1 + 24576000L;           // 8 x 1024x1024 f16
    _Float16* wsWc = wsW + 8L * 1048576L;        // 4 x 64x1024 f16 (cls W splits)
    float* kth = (float*)(wsWc + 4L * 65536L);   // 1280 f32

    dim3 blk(256);
    dim3 gg(1504);

    split_w4<<<dim3(2048), blk, 0, stream>>>(Wfc_r, Wfc1_r, Wfc_f, Wfc1_f, wsW);
    split_clsW2<<<dim3(512), blk, 0, stream>>>(Wcls_r, Wra, Wcls_f, Wfa, wsWc);

    // ---- RGB stream ----
    gemm_l1_f32a<<<gg, blk, 0, stream>>>(inp, wsW + 0L * 1048576, wsW + 1L * 1048576,
                                         bfc_r, wsH0, wsH1);
    gemm_fused_f16<2><<<gg, blk, 0, stream>>>(wsH0, wsH1, wsW + 2L * 1048576, wsW + 3L * 1048576,
                                              bfc1_r, out + OFF_XR, wsA0, wsA1);
    cls_mfma_f16<<<dim3(375), blk, 0, stream>>>(wsA0, wsA1, wsWc + 0L * 65536, wsWc + 1L * 65536,
                                                bcls_r, bra, out + OFF_CLSX_R, out + OFF_CLSRA);

    // ---- Flow stream ----
    gemm_l1_f32a<<<gg, blk, 0, stream>>>(inp + DDIM, wsW + 4L * 1048576, wsW + 5L * 1048576,
                                         bfc_f, wsH0, wsH1);
    gemm_fused_f16<2><<<gg, blk, 0, stream>>>(wsH0, wsH1, wsW + 6L * 1048576, wsW + 7L * 1048576,
                                              bfc1_f, out + OFF_XF, wsA0, wsA1);
    cls_mfma_f16<<<dim3(375), blk, 0, stream>>>(wsA0, wsA1, wsWc + 2L * 65536, wsWc + 3L * 65536,
                                                bcls_f, bfa, out + OFF_CLSX_F, out + OFF_CLSFA);

    select_kth<<<dim3(1280), blk, 0, stream>>>(out + OFF_CLSX_R, out + OFF_CLSX_F, kth);
    final_mask<<<dim3((NBATCH * TDIM * CDIM + 255) / 256), blk, 0, stream>>>(out, kth, mul_r, mul_f);
}